// Round 6
// baseline (32.562 us; speedup 1.0000x reference)
//
#include <hip/hip_runtime.h>

// z (8, 8192, 256) fp32; width=9 (half=4), fixed by setup_inputs.
// out = z * exp(z) / denom, denom[b,n] = 9-window sum over n of
//       s[b,n] = sum_c exp(z[b,n,c]), zero-padded at batch edges.
//
// Barrier-free streaming, occupancy-tuned: one wave owns an 8-row strip,
// register rings p[16] (per-lane exp partials) + w[8] (z*exp(z) stash),
// ~<=85 VGPR via __launch_bounds__ min-waves=6 -> 24 waves/CU resident.
// Halo rows (4 each side) recomputed; neighbor-shared -> L2/L3 hits.

typedef float f32x4 __attribute__((ext_vector_type(4)));

static constexpr int kB      = 8;
static constexpr int kN      = 8192;
static constexpr int kC      = 256;              // contiguous innermost
static constexpr int STRIP   = 8;                // output rows per wave
static constexpr int HALF    = 4;                // width 9 -> half 4
static constexpr int NROWS   = STRIP + 2 * HALF; // 16 rows touched per wave
static constexpr int THREADS = 256;              // 4 waves per block
static constexpr int WPB     = THREADS / 64;

__global__ void __launch_bounds__(THREADS, 6)
stream_spatial_softmax(const float* __restrict__ z, float* __restrict__ out) {
    const int wave = threadIdx.x >> 6;
    const int lane = threadIdx.x & 63;
    const int strip = blockIdx.x * WPB + wave;          // 0..8191
    const int stripsPerBatch = kN / STRIP;              // 1024
    const int b  = strip >> 10;                         // strip / 1024
    const int n0 = (strip & (stripsPerBatch - 1)) * STRIP;

    const float* zb = z   + (size_t)b * kN * kC;
    float*       ob = out + (size_t)b * kN * kC;

    float p[NROWS];     // per-lane partial exp-sums, rows n0-4 .. n0+11
    f32x4 w[STRIP];     // z*exp(z) stash for main rows

#pragma unroll
    for (int j = 0; j < NROWS; ++j) {
        const int n    = n0 + j - HALF;
        const bool inb = (n >= 0) && (n < kN);           // wave-uniform
        const int nc   = inb ? n : (n < 0 ? 0 : kN - 1); // clamp: load unconditional
        const f32x4 v  = reinterpret_cast<const f32x4*>(zb + (size_t)nc * kC)[lane];
        const float e0 = __expf(v.x), e1 = __expf(v.y),
                    e2 = __expf(v.z), e3 = __expf(v.w);
        p[j] = inb ? ((e0 + e1) + (e2 + e3)) : 0.0f;

        const int m = j - HALF;             // main-row index (static per j)
        if (m >= 0 && m < STRIP) {          // compile-time guard after unroll
            w[m].x = v.x * e0; w[m].y = v.y * e1;
            w[m].z = v.z * e2; w[m].w = v.w * e3;
        }

        // output row t is ready once row t+4 (= j - 2*HALF + 8) is in p[]
        const int t = j - 2 * HALF;         // static per j
        if (t >= 0) {
            float win = 0.0f;
#pragma unroll
            for (int k = 0; k < 2 * HALF + 1; ++k) win += p[t + k];
#pragma unroll
            for (int off = 32; off >= 1; off >>= 1) win += __shfl_xor(win, off);
            const float rinv = __builtin_amdgcn_rcpf(win);
            const f32x4 o = w[t] * rinv;
            reinterpret_cast<f32x4*>(ob + (size_t)(n0 + t) * kC)[lane] = o;
        }
    }
}

extern "C" void kernel_launch(void* const* d_in, const int* in_sizes, int n_in,
                              void* d_out, int out_size, void* d_ws, size_t ws_size,
                              hipStream_t stream) {
    const float* z   = (const float*)d_in[0];
    float*       out = (float*)d_out;

    const int strips = (kB * kN) / STRIP;   // 8192
    const int blocks = strips / WPB;        // 2048
    stream_spatial_softmax<<<blocks, THREADS, 0, stream>>>(z, out);
}

// Round 7
// 28.056 us; speedup vs baseline: 1.1606x; 1.1606x over previous
//
#include <hip/hip_runtime.h>

// z (8, 8192, 256) fp32; width=9 (half=4), fixed by setup_inputs.
// out = z * exp(z) / denom, denom[b,n] = 9-window sum over n of
//       s[b,n] = sum_c exp(z[b,n,c]), zero-padded at batch edges.
//
// Barrier-free streaming (R5 structure) with reduced register state:
//  - f16 stash of w = z*exp(z)  (16 VGPR instead of 64)
//  - XCD-aware block swizzle: each XCD owns one batch -> halo re-reads
//    are same-XCD L2 hits
//  - clamp-unconditional loads, nontemporal f32x4 stores

typedef float    f32x4 __attribute__((ext_vector_type(4)));
typedef _Float16 f16x4 __attribute__((ext_vector_type(4)));

static constexpr int kB      = 8;
static constexpr int kN      = 8192;
static constexpr int kC      = 256;              // contiguous innermost
static constexpr int STRIP   = 16;               // output rows per wave
static constexpr int HALF    = 4;                // width 9 -> half 4
static constexpr int NROWS   = STRIP + 2 * HALF; // 24 rows touched per wave
static constexpr int THREADS = 256;              // 4 waves per block
static constexpr int WPB     = THREADS / 64;
static constexpr int NXCD    = 8;

__global__ void __launch_bounds__(THREADS, 4)
stream_spatial_softmax(const float* __restrict__ z, float* __restrict__ out) {
    const int wave = threadIdx.x >> 6;
    const int lane = threadIdx.x & 63;

    // XCD swizzle: nwg=1024, divisible by 8 -> bijective chunked remap.
    // XCD x receives swizzled ids [x*128, (x+1)*128) == one full batch.
    const int nwg  = gridDim.x;                 // 1024
    const int cpx  = nwg / NXCD;                // 128
    const int swz  = (blockIdx.x % NXCD) * cpx + blockIdx.x / NXCD;

    const int strip = swz * WPB + wave;          // 0..4095
    const int stripsPerBatch = kN / STRIP;       // 512
    const int b  = strip / stripsPerBatch;
    const int n0 = (strip % stripsPerBatch) * STRIP;

    const float* zb = z   + (size_t)b * kN * kC;
    float*       ob = out + (size_t)b * kN * kC;

    float p[NROWS];     // per-lane partial exp-sums, rows n0-4 .. n0+19
    f16x4 w[STRIP];     // z*exp(z) stash (f16) for main rows

#pragma unroll
    for (int j = 0; j < NROWS; ++j) {
        const int n    = n0 + j - HALF;
        const bool inb = (n >= 0) && (n < kN);           // wave-uniform
        const int nc   = inb ? n : (n < 0 ? 0 : kN - 1); // clamp: load unconditional
        const f32x4 v  = reinterpret_cast<const f32x4*>(zb + (size_t)nc * kC)[lane];
        const float e0 = __expf(v.x), e1 = __expf(v.y),
                    e2 = __expf(v.z), e3 = __expf(v.w);
        p[j] = inb ? ((e0 + e1) + (e2 + e3)) : 0.0f;

        const int m = j - HALF;             // main-row index (static per j)
        if (m >= 0 && m < STRIP) {          // compile-time guard after unroll
            w[m].x = (_Float16)(v.x * e0);
            w[m].y = (_Float16)(v.y * e1);
            w[m].z = (_Float16)(v.z * e2);
            w[m].w = (_Float16)(v.w * e3);
        }

        // output row t is ready once row t+4 (= j - 2*HALF + 8) is in p[]
        const int t = j - 2 * HALF;         // static per j
        if (t >= 0) {
            float win = 0.0f;
#pragma unroll
            for (int k = 0; k < 2 * HALF + 1; ++k) win += p[t + k];
#pragma unroll
            for (int off = 32; off >= 1; off >>= 1) win += __shfl_xor(win, off);
            const float rinv = __builtin_amdgcn_rcpf(win);
            f32x4 o;
            o.x = (float)w[t].x * rinv;
            o.y = (float)w[t].y * rinv;
            o.z = (float)w[t].z * rinv;
            o.w = (float)w[t].w * rinv;
            __builtin_nontemporal_store(o,
                reinterpret_cast<f32x4*>(ob + (size_t)(n0 + t) * kC) + lane);
        }
    }
}

extern "C" void kernel_launch(void* const* d_in, const int* in_sizes, int n_in,
                              void* d_out, int out_size, void* d_ws, size_t ws_size,
                              hipStream_t stream) {
    const float* z   = (const float*)d_in[0];
    float*       out = (float*)d_out;

    const int strips = (kB * kN) / STRIP;   // 4096
    const int blocks = strips / WPB;        // 1024
    stream_spatial_softmax<<<blocks, THREADS, 0, stream>>>(z, out);
}

// Round 8
// 27.478 us; speedup vs baseline: 1.1850x; 1.0210x over previous
//
#include <hip/hip_runtime.h>

// z (8, 8192, 256) fp32; width=9 (half=4), fixed by setup_inputs.
// out = z * exp(z) / denom, denom[b,n] = 9-window sum over n of
//       s[b,n] = sum_c exp(z[b,n,c]), zero-padded at batch edges.
//
// R7 structure + explicit 4-deep load-prefetch ring: each wave keeps 4
// row-loads (1 KB each) in flight to raise memory-level parallelism.
// f16 stash of z*exp(z), XCD-aware swizzle, nontemporal stores.

typedef float    f32x4 __attribute__((ext_vector_type(4)));
typedef _Float16 f16x4 __attribute__((ext_vector_type(4)));

static constexpr int kB      = 8;
static constexpr int kN      = 8192;
static constexpr int kC      = 256;              // contiguous innermost
static constexpr int STRIP   = 16;               // output rows per wave
static constexpr int HALF    = 4;                // width 9 -> half 4
static constexpr int NROWS   = STRIP + 2 * HALF; // 24 rows touched per wave
static constexpr int THREADS = 256;              // 4 waves per block
static constexpr int WPB     = THREADS / 64;
static constexpr int NXCD    = 8;
static constexpr int PF      = 4;                // prefetch depth (loads in flight)

__global__ void __launch_bounds__(THREADS, 4)
stream_spatial_softmax(const float* __restrict__ z, float* __restrict__ out) {
    const int wave = threadIdx.x >> 6;
    const int lane = threadIdx.x & 63;

    // XCD swizzle: nwg=1024 divisible by 8 -> bijective chunked remap;
    // each XCD owns one full batch -> halo re-reads are same-XCD L2 hits.
    const int nwg  = gridDim.x;                 // 1024
    const int cpx  = nwg / NXCD;                // 128
    const int swz  = (blockIdx.x % NXCD) * cpx + blockIdx.x / NXCD;

    const int strip = swz * WPB + wave;          // 0..4095
    const int stripsPerBatch = kN / STRIP;       // 512
    const int b  = strip / stripsPerBatch;
    const int n0 = (strip % stripsPerBatch) * STRIP;

    const float* zb = z   + (size_t)b * kN * kC;
    float*       ob = out + (size_t)b * kN * kC;

    auto rowptr = [&](int j) {
        const int n  = n0 + j - HALF;
        const int nc = (n < 0) ? 0 : (n >= kN ? kN - 1 : n);  // clamp
        return reinterpret_cast<const f32x4*>(zb + (size_t)nc * kC) + lane;
    };

    f32x4 vr[PF];       // prefetch ring: PF loads in flight
    float p[NROWS];     // per-lane partial exp-sums (short static live ranges)
    f16x4 w[STRIP];     // z*exp(z) stash (f16)

#pragma unroll
    for (int j = 0; j < PF; ++j) vr[j] = *rowptr(j);   // prime the ring

#pragma unroll
    for (int j = 0; j < NROWS; ++j) {
        const f32x4 v = vr[j % PF];                    // grab (static index)
        if (j + PF < NROWS) vr[j % PF] = *rowptr(j + PF);  // refill slot

        const int  n   = n0 + j - HALF;
        const bool inb = (n >= 0) && (n < kN);         // wave-uniform
        const float e0 = __expf(v.x), e1 = __expf(v.y),
                    e2 = __expf(v.z), e3 = __expf(v.w);
        p[j] = inb ? ((e0 + e1) + (e2 + e3)) : 0.0f;

        const int m = j - HALF;             // main-row index (static per j)
        if (m >= 0 && m < STRIP) {
            w[m].x = (_Float16)(v.x * e0);
            w[m].y = (_Float16)(v.y * e1);
            w[m].z = (_Float16)(v.z * e2);
            w[m].w = (_Float16)(v.w * e3);
        }

        const int t = j - 2 * HALF;         // output row ready (static per j)
        if (t >= 0) {
            float win = 0.0f;
#pragma unroll
            for (int k = 0; k < 2 * HALF + 1; ++k) win += p[t + k];
#pragma unroll
            for (int off = 32; off >= 1; off >>= 1) win += __shfl_xor(win, off);
            const float rinv = __builtin_amdgcn_rcpf(win);
            f32x4 o;
            o.x = (float)w[t].x * rinv;
            o.y = (float)w[t].y * rinv;
            o.z = (float)w[t].z * rinv;
            o.w = (float)w[t].w * rinv;
            __builtin_nontemporal_store(o,
                reinterpret_cast<f32x4*>(ob + (size_t)(n0 + t) * kC) + lane);
        }
    }
}

extern "C" void kernel_launch(void* const* d_in, const int* in_sizes, int n_in,
                              void* d_out, int out_size, void* d_ws, size_t ws_size,
                              hipStream_t stream) {
    const float* z   = (const float*)d_in[0];
    float*       out = (float*)d_out;

    const int strips = (kB * kN) / STRIP;   // 4096
    const int blocks = strips / WPB;        // 1024
    stream_spatial_softmax<<<blocks, THREADS, 0, stream>>>(z, out);
}